// Round 7
// baseline (739.415 us; speedup 1.0000x reference)
//
#include <hip/hip_runtime.h>

#define N_DRUG 20000
#define N_DIS  10000
#define N_ATTR 2000
#define T_ATTR 8
#define E_MT   500000
#define E_HA   100000
#define E_LBL  200000
#define HC     128
#define NB     16    // edge-chunk blocks per sub-segment in CSR build
#define SBW    5000  // source-block width (rows): 5000*512B = 2.56MB < 4MB L2/XCD

__device__ __forceinline__ float leakyf(float x) { return x >= 0.f ? x : 0.01f * x; }

// ---------------- CSR build with source-blocked sub-segments ----------------
// 46 sub-segments s:
//   s0-3  : z0 mt_dst key (bins 10000), gather-src mt_src (drug), 4 blocks of 5000
//   s4-5  : z1 mt_src key (bins 20000), gather-src mt_dst (dis),  2 blocks of 5000
//   s6-37 : z2+t ha_dst[t] key (bins 2000), gather-src ha_src (drug), 4 blocks (t=(s-6)>>2, b=(s-6)&3)
//   s38-45: z10+t ha_src[t] key (bins 20000), gather-src ha_dst (attr), 1 block
// off is FLAT per z over (b-major, dst) + one sentinel per z:
#define OFF_Z0 0
#define OFF_Z1 40001
#define OFF_Z2(t) (80002 + (t) * 8001)
#define OFF_Z10(t) (144010 + (t) * 20001)
#define OFF_TOT 304018
// hist: NB chunk-blocks x bins per sub-segment, flat; prefix in "bins" units per s below.

struct SS { const int* key; const int* oth; int n; int bins; int obase; int hbase; int srcLo; int srcHi; int* val; };

__device__ __forceinline__ SS ss_resolve(int s,
    const int* mt_src, const int* mt_dst, const int* ha_src, const int* ha_dst,
    int* vmd, int* vms, int* vhd, int* vhs) {
  SS r;
  if (s < 4) {
    r.key = mt_dst; r.oth = mt_src; r.n = E_MT; r.bins = N_DIS;
    r.obase = OFF_Z0 + s * N_DIS;  r.hbase = NB * (0 + s * N_DIS);
    r.srcLo = s * SBW; r.srcHi = r.srcLo + SBW; r.val = vmd;
  } else if (s < 6) {
    int b = s - 4;
    r.key = mt_src; r.oth = mt_dst; r.n = E_MT; r.bins = N_DRUG;
    r.obase = OFF_Z1 + b * N_DRUG; r.hbase = NB * (40000 + b * N_DRUG);
    r.srcLo = b * SBW; r.srcHi = r.srcLo + SBW; r.val = vms;
  } else if (s < 38) {
    int q = s - 6; int t = q >> 2, b = q & 3;
    r.key = ha_dst + (size_t)t * E_HA; r.oth = ha_src + (size_t)t * E_HA; r.n = E_HA; r.bins = N_ATTR;
    r.obase = OFF_Z2(t) + b * N_ATTR; r.hbase = NB * (80000 + q * N_ATTR);
    r.srcLo = b * SBW; r.srcHi = r.srcLo + SBW; r.val = vhd + (size_t)t * E_HA;
  } else {
    int t = s - 38;
    r.key = ha_src + (size_t)t * E_HA; r.oth = ha_dst + (size_t)t * E_HA; r.n = E_HA; r.bins = N_DRUG;
    r.obase = OFF_Z10(t); r.hbase = NB * (144000 + t * N_DRUG);
    r.srcLo = 0; r.srcHi = N_ATTR; r.val = vhs + (size_t)t * E_HA;
  }
  return r;
}

__global__ __launch_bounds__(256) void k_hist(
    const int* __restrict__ mt_src, const int* __restrict__ mt_dst,
    const int* __restrict__ ha_src, const int* __restrict__ ha_dst,
    int* __restrict__ hist,
    int* vmd, int* vms, int* vhd, int* vhs) {
  SS s = ss_resolve(blockIdx.z, mt_src, mt_dst, ha_src, ha_dst, vmd, vms, vhd, vhs);
  __shared__ int h[N_DRUG];
  int tid = threadIdx.x, b = blockIdx.x;
  for (int i = tid; i < s.bins; i += 256) h[i] = 0;
  __syncthreads();
  int ch = (s.n + NB - 1) / NB;
  int lo = b * ch, hi = min(s.n, lo + ch);
  for (int i = lo + tid; i < hi; i += 256) {
    int o = s.oth[i];
    if (o >= s.srcLo && o < s.srcHi) atomicAdd(&h[s.key[i]], 1);
  }
  __syncthreads();
  int* hz = hist + s.hbase + (size_t)b * s.bins;
  for (int i = tid; i < s.bins; i += 256) hz[i] = h[i];
}

// thread = bin: coalesced per-bin prefix over NB chunk-blocks; bin total -> off[obase+i]
__global__ __launch_bounds__(256) void k_blkpfx(
    const int* __restrict__ mt_src, const int* __restrict__ mt_dst,
    const int* __restrict__ ha_src, const int* __restrict__ ha_dst,
    int* __restrict__ hist, int* __restrict__ off,
    int* vmd, int* vms, int* vhd, int* vhs) {
  SS s = ss_resolve(blockIdx.z, mt_src, mt_dst, ha_src, ha_dst, vmd, vms, vhd, vhs);
  int i = blockIdx.x * 256 + threadIdx.x;
  if (i >= s.bins) return;
  int run = 0;
  #pragma unroll
  for (int b = 0; b < NB; b++) {
    int idx = s.hbase + b * s.bins + i;
    int v = hist[idx];
    hist[idx] = run;
    run += v;
  }
  off[s.obase + i] = run;
}

// block = z (18): in-place exclusive scan over the z's FLAT (b,dst) counts; sentinel = total
__global__ __launch_bounds__(1024) void k_scan_bins(int* __restrict__ off) {
  int z = blockIdx.x;
  int zbase, L;
  if (z == 0)      { zbase = OFF_Z0;  L = 40000; }
  else if (z == 1) { zbase = OFF_Z1;  L = 40000; }
  else if (z < 10) { int t = z - 2;  zbase = OFF_Z2(t);  L = 8000; }
  else             { int t = z - 10; zbase = OFF_Z10(t); L = 20000; }
  __shared__ int ssum[1024];
  int tid = threadIdx.x;
  int per = (L + 1023) >> 10;
  int lo = min(L, tid * per), hi = min(L, lo + per);
  int s = 0;
  for (int i = lo; i < hi; i++) s += off[zbase + i];
  ssum[tid] = s;
  __syncthreads();
  if (tid == 0) {
    int run = 0;
    for (int i = 0; i < 1024; i++) { int v = ssum[i]; ssum[i] = run; run += v; }
    off[zbase + L] = run;
  }
  __syncthreads();
  int run = ssum[tid];
  for (int i = lo; i < hi; i++) {
    int v = off[zbase + i];
    off[zbase + i] = run;
    run += v;
  }
}

__global__ __launch_bounds__(256) void k_fill2(
    const int* __restrict__ mt_src, const int* __restrict__ mt_dst,
    const int* __restrict__ ha_src, const int* __restrict__ ha_dst,
    const int* __restrict__ hist, const int* __restrict__ off,
    int* vmd, int* vms, int* vhd, int* vhs) {
  SS s = ss_resolve(blockIdx.z, mt_src, mt_dst, ha_src, ha_dst, vmd, vms, vhd, vhs);
  __shared__ int h[N_DRUG];
  int tid = threadIdx.x, b = blockIdx.x;
  const int* hz = hist + s.hbase + (size_t)b * s.bins;
  const int* oz = off + s.obase;
  for (int i = tid; i < s.bins; i += 256) h[i] = hz[i] + oz[i];
  __syncthreads();
  int ch = (s.n + NB - 1) / NB;
  int lo = b * ch, hi = min(s.n, lo + ch);
  for (int i = lo + tid; i < hi; i += 256) {
    int o = s.oth[i];
    if (o >= s.srcLo && o < s.srcHi) {
      int pos = atomicAdd(&h[s.key[i]], 1);
      s.val[pos] = o;
    }
  }
}

// ---------------- x_dis init ----------------
__global__ void k_dis0(const float* __restrict__ dx, const float* __restrict__ w,
                       const float* __restrict__ b, const float* __restrict__ emb,
                       float* __restrict__ out) {
  int i = blockIdx.x;
  int j = threadIdx.x;
  float s = b[j] + emb[(size_t)i * HC + j];
  #pragma unroll
  for (int k = 0; k < 10; k++) s += dx[i * 10 + k] * w[k * HC + j];
  out[(size_t)i * HC + j] = s;
}

// ---------------- Wc = rmt_wr + sum_t rha_wr ; biasc = rmt_bl + sum_t rha_bl ----------------
__global__ void k_wc(const float* __restrict__ wr_main, const float* __restrict__ wr_t,
                     const float* __restrict__ bl_main, const float* __restrict__ bl_t,
                     float* __restrict__ Wc, float* __restrict__ biasc) {
  int i = blockIdx.x * blockDim.x + threadIdx.x;
  if (i < HC * HC) {
    float s = wr_main[i];
    #pragma unroll
    for (int t = 0; t < T_ATTR; t++) s += wr_t[(size_t)t * HC * HC + i];
    Wc[i] = s;
  }
  if (i < HC) {
    float s = bl_main[i];
    #pragma unroll
    for (int t = 0; t < T_ATTR; t++) s += bl_t[t * HC + i];
    biasc[i] = s;
  }
}

// ---------------- unroll-8 gather accumulate ----------------
__device__ __forceinline__ void gacc(const float* __restrict__ X, const int* __restrict__ val,
                                     int b, int e, int lane2, float& ax, float& ay) {
  int i = b;
  for (; i + 8 <= e; i += 8) {
    float2 v[8];
    #pragma unroll
    for (int q = 0; q < 8; q++) {
      int n = val[i + q];
      v[q] = *(const float2*)(X + (size_t)n * HC + lane2);
    }
    #pragma unroll
    for (int q = 0; q < 8; q++) { ax += v[q].x; ay += v[q].y; }
  }
  for (; i < e; i++) {
    int n = val[i];
    float2 v = *(const float2*)(X + (size_t)n * HC + lane2);
    ax += v.x; ay += v.y;
  }
}

// ---------------- mega segment-mean: all gathers of one layer, source-block phased ----------------
// wave w: [0,16000) m2a (xd, 4 blocks) | [16000,26000) m2dis (xd, 4 blocks) | [26000,46000) drug (Ydis 2 blocks + Yattr)
__global__ __launch_bounds__(256) void k_seg_mega(
    const int* __restrict__ off,
    const int* __restrict__ vmt_dst, const int* __restrict__ vmt_src,
    const int* __restrict__ vha_dst, const int* __restrict__ vha_src,
    const float* __restrict__ xd, const float* __restrict__ Ydis,
    const float* __restrict__ Yattr,
    float* __restrict__ m2dis, float* __restrict__ accd, float* __restrict__ m2a) {
  int lane2 = (threadIdx.x & 63) * 2;
  int w = blockIdx.x * 4 + (threadIdx.x >> 6);
  if (w < 16000) {
    int t = w / N_ATTR, r = w - t * N_ATTR;
    int base = OFF_Z2(t) + r;
    const int* vz = vha_dst + (size_t)t * E_HA;
    float ax = 0.f, ay = 0.f; int c = 0;
    #pragma unroll
    for (int b = 0; b < 4; b++) {
      int lo = off[base + b * N_ATTR], hi = off[base + b * N_ATTR + 1];
      c += hi - lo;
      gacc(xd, vz, lo, hi, lane2, ax, ay);
    }
    float inv = 1.f / (float)(c > 0 ? c : 1);
    *(float2*)(m2a + ((size_t)t * N_ATTR + r) * HC + lane2) = make_float2(ax * inv, ay * inv);
  } else if (w < 26000) {
    int d = w - 16000;
    float ax = 0.f, ay = 0.f; int c = 0;
    #pragma unroll
    for (int b = 0; b < 4; b++) {
      int lo = off[OFF_Z0 + b * N_DIS + d], hi = off[OFF_Z0 + b * N_DIS + d + 1];
      c += hi - lo;
      gacc(xd, vmt_dst, lo, hi, lane2, ax, ay);
    }
    float inv = 1.f / (float)(c > 0 ? c : 1);
    *(float2*)(m2dis + (size_t)d * HC + lane2) = make_float2(ax * inv, ay * inv);
  } else {
    int d = w - 26000;
    float sx = 0.f, sy = 0.f;
    {
      float ax = 0.f, ay = 0.f; int c = 0;
      #pragma unroll
      for (int b = 0; b < 2; b++) {
        int lo = off[OFF_Z1 + b * N_DRUG + d], hi = off[OFF_Z1 + b * N_DRUG + d + 1];
        c += hi - lo;
        gacc(Ydis, vmt_src, lo, hi, lane2, ax, ay);
      }
      float inv = 1.f / (float)(c > 0 ? c : 1);
      sx += ax * inv; sy += ay * inv;
    }
    for (int t = 0; t < T_ATTR; t++) {
      int lo = off[OFF_Z10(t) + d], hi = off[OFF_Z10(t) + d + 1];
      float ax = 0.f, ay = 0.f;
      gacc(Yattr + (size_t)t * N_ATTR * HC, vha_src + (size_t)t * E_HA, lo, hi, lane2, ax, ay);
      int c = hi - lo;
      float inv = 1.f / (float)(c > 0 ? c : 1);
      sx += ax * inv; sy += ay * inv;
    }
    *(float2*)(accd + (size_t)d * HC + lane2) = make_float2(sx, sy);
  }
}

// ---------------- generalized batched GEMM ----------------
struct GemmJob {
  const float* A1; const float* B1;
  const float* A2; const float* B2;
  const float* bias; const float* ACC;
  float* D;
  int M; int leaky;
};
struct GemmJobs { GemmJob j[10]; };

__global__ __launch_bounds__(256) void k_gemm_multi(GemmJobs jobs) {
  GemmJob jb = jobs.j[blockIdx.z];
  int m0 = blockIdx.x * 64;
  if (m0 >= jb.M) return;
  __shared__ float As[16][68];
  __shared__ float Bs[16][132];
  int tid = threadIdx.x;
  int tx = tid & 31, ty = tid >> 5;
  float acc[8][4];
  #pragma unroll
  for (int i = 0; i < 8; i++)
    #pragma unroll
    for (int j = 0; j < 4; j++) acc[i][j] = 0.f;

  int K = jb.A2 ? 256 : 128;
  for (int kk = 0; kk < K; kk += 16) {
    const float* A = (kk < 128) ? jb.A1 : jb.A2;
    const float* B = (kk < 128) ? jb.B1 : jb.B2;
    int kb = kk & 127;
    {
      int r = tid >> 2, kq = (tid & 3) * 4;
      int gr = m0 + r;
      float4 v = make_float4(0.f, 0.f, 0.f, 0.f);
      if (gr < jb.M) v = *(const float4*)(A + (size_t)gr * HC + kb + kq);
      As[kq + 0][r] = v.x; As[kq + 1][r] = v.y; As[kq + 2][r] = v.z; As[kq + 3][r] = v.w;
    }
    #pragma unroll
    for (int i = 0; i < 2; i++) {
      int idx = i * 256 + tid;
      int k = idx >> 5, c = (idx & 31) * 4;
      *(float4*)&Bs[k][c] = *(const float4*)(B + (size_t)(kb + k) * HC + c);
    }
    __syncthreads();
    #pragma unroll
    for (int k = 0; k < 16; k++) {
      float4 a0 = *(const float4*)&As[k][ty * 8];
      float4 a1 = *(const float4*)&As[k][ty * 8 + 4];
      float4 bv = *(const float4*)&Bs[k][tx * 4];
      float av[8] = {a0.x, a0.y, a0.z, a0.w, a1.x, a1.y, a1.z, a1.w};
      float bb[4] = {bv.x, bv.y, bv.z, bv.w};
      #pragma unroll
      for (int i = 0; i < 8; i++)
        #pragma unroll
        for (int j = 0; j < 4; j++) acc[i][j] += av[i] * bb[j];
    }
    __syncthreads();
  }

  int c0 = tx * 4;
  float4 bs = make_float4(0.f, 0.f, 0.f, 0.f);
  if (jb.bias) bs = *(const float4*)(jb.bias + c0);
  #pragma unroll
  for (int i = 0; i < 8; i++) {
    int gr = m0 + ty * 8 + i;
    if (gr >= jb.M) break;
    float r0 = acc[i][0] + bs.x, r1 = acc[i][1] + bs.y, r2 = acc[i][2] + bs.z, r3 = acc[i][3] + bs.w;
    if (jb.ACC) {
      float4 ac = *(const float4*)(jb.ACC + (size_t)gr * HC + c0);
      r0 += ac.x; r1 += ac.y; r2 += ac.z; r3 += ac.w;
    }
    if (jb.leaky) { r0 = leakyf(r0); r1 = leakyf(r1); r2 = leakyf(r2); r3 = leakyf(r3); }
    float4 rv = make_float4(r0, r1, r2, r3);
    *(float4*)(jb.D + (size_t)gr * 128 + c0) = rv;
  }
}

// ---------------- classifier head GEMMs ----------------
struct G64Job { const float* X; const float* W; const float* bias; float* D; int M; };

__global__ __launch_bounds__(256) void k_gemm64(G64Job j0, G64Job j1) {
  G64Job jb = blockIdx.z ? j1 : j0;
  int m0 = blockIdx.x * 64;
  if (m0 >= jb.M) return;
  __shared__ float As[16][68];
  __shared__ float Bs[16][68];
  int tid = threadIdx.x;
  int tx = tid & 15, ty = tid >> 4;
  float acc[4][4];
  #pragma unroll
  for (int i = 0; i < 4; i++)
    #pragma unroll
    for (int j = 0; j < 4; j++) acc[i][j] = 0.f;

  for (int kk = 0; kk < 128; kk += 16) {
    {
      int r = tid >> 2, kq = (tid & 3) * 4;
      int gr = m0 + r;
      float4 v = make_float4(0.f, 0.f, 0.f, 0.f);
      if (gr < jb.M) v = *(const float4*)(jb.X + (size_t)gr * HC + kk + kq);
      As[kq + 0][r] = v.x; As[kq + 1][r] = v.y; As[kq + 2][r] = v.z; As[kq + 3][r] = v.w;
    }
    {
      int k = tid >> 4, c = (tid & 15) * 4;
      *(float4*)&Bs[k][c] = *(const float4*)(jb.W + (size_t)(kk + k) * 64 + c);
    }
    __syncthreads();
    #pragma unroll
    for (int k = 0; k < 16; k++) {
      float4 a = *(const float4*)&As[k][ty * 4];
      float4 b = *(const float4*)&Bs[k][tx * 4];
      float av[4] = {a.x, a.y, a.z, a.w};
      float bb[4] = {b.x, b.y, b.z, b.w};
      #pragma unroll
      for (int i = 0; i < 4; i++)
        #pragma unroll
        for (int j = 0; j < 4; j++) acc[i][j] += av[i] * bb[j];
    }
    __syncthreads();
  }
  float4 bs = make_float4(0.f, 0.f, 0.f, 0.f);
  if (jb.bias) bs = *(const float4*)(jb.bias + tx * 4);
  #pragma unroll
  for (int i = 0; i < 4; i++) {
    int gr = m0 + ty * 4 + i;
    if (gr < jb.M) {
      float4 r = make_float4(acc[i][0] + bs.x, acc[i][1] + bs.y, acc[i][2] + bs.z, acc[i][3] + bs.w);
      *(float4*)(jb.D + (size_t)gr * 64 + tx * 4) = r;
    }
  }
}

// ---------------- per-edge tail MLP (LDS weights, fully unrolled, registers only) ----------------
__global__ __launch_bounds__(256) void k_tail(
    const float* __restrict__ U, const float* __restrict__ V,
    const int* __restrict__ es, const int* __restrict__ ed,
    const float* __restrict__ cw1, const float* __restrict__ cb1,
    const float* __restrict__ cw2, const float* __restrict__ cb2,
    const float* __restrict__ cw3, const float* __restrict__ cb3,
    const float* __restrict__ cw4, const float* __restrict__ cb4,
    float* __restrict__ out, int n) {
  __shared__ float w1[64 * 32];
  __shared__ float w2[32 * 16];
  __shared__ float w3[16 * 8];
  __shared__ float w4[8];
  __shared__ float b1[32], b2[16], b3[8];
  int tid = threadIdx.x;
  #pragma unroll
  for (int q = 0; q < 8; q++) w1[tid + q * 256] = cw1[tid + q * 256];
  #pragma unroll
  for (int q = 0; q < 2; q++) w2[tid + q * 256] = cw2[tid + q * 256];
  if (tid < 128) w3[tid] = cw3[tid];
  if (tid < 8)  w4[tid] = cw4[tid];
  if (tid < 32) b1[tid] = cb1[tid];
  if (tid < 16) b2[tid] = cb2[tid];
  if (tid < 8)  b3[tid] = cb3[tid];
  __syncthreads();
  int i = blockIdx.x * 256 + tid;
  if (i >= n) return;
  int s = es[i], d = ed[i];
  const float4* up = (const float4*)(U + (size_t)s * 64);
  const float4* vp = (const float4*)(V + (size_t)d * 64);
  float h1[64];
  #pragma unroll
  for (int q = 0; q < 16; q++) {
    float4 a = up[q], b = vp[q];
    h1[4 * q + 0] = leakyf(a.x + b.x);
    h1[4 * q + 1] = leakyf(a.y + b.y);
    h1[4 * q + 2] = leakyf(a.z + b.z);
    h1[4 * q + 3] = leakyf(a.w + b.w);
  }
  float h2[32];
  #pragma unroll
  for (int j = 0; j < 32; j++) h2[j] = b1[j];
  #pragma unroll
  for (int k = 0; k < 64; k++) {
    float hv = h1[k];
    #pragma unroll
    for (int jq = 0; jq < 8; jq++) {
      float4 w = *(const float4*)&w1[k * 32 + jq * 4];
      h2[4 * jq + 0] = fmaf(hv, w.x, h2[4 * jq + 0]);
      h2[4 * jq + 1] = fmaf(hv, w.y, h2[4 * jq + 1]);
      h2[4 * jq + 2] = fmaf(hv, w.z, h2[4 * jq + 2]);
      h2[4 * jq + 3] = fmaf(hv, w.w, h2[4 * jq + 3]);
    }
  }
  float h3[16];
  #pragma unroll
  for (int j = 0; j < 16; j++) h3[j] = b2[j];
  #pragma unroll
  for (int k = 0; k < 32; k++) {
    float hv = leakyf(h2[k]);
    #pragma unroll
    for (int jq = 0; jq < 4; jq++) {
      float4 w = *(const float4*)&w2[k * 16 + jq * 4];
      h3[4 * jq + 0] = fmaf(hv, w.x, h3[4 * jq + 0]);
      h3[4 * jq + 1] = fmaf(hv, w.y, h3[4 * jq + 1]);
      h3[4 * jq + 2] = fmaf(hv, w.z, h3[4 * jq + 2]);
      h3[4 * jq + 3] = fmaf(hv, w.w, h3[4 * jq + 3]);
    }
  }
  float h4[8];
  #pragma unroll
  for (int j = 0; j < 8; j++) h4[j] = b3[j];
  #pragma unroll
  for (int k = 0; k < 16; k++) {
    float hv = leakyf(h3[k]);
    #pragma unroll
    for (int jq = 0; jq < 2; jq++) {
      float4 w = *(const float4*)&w3[k * 8 + jq * 4];
      h4[4 * jq + 0] = fmaf(hv, w.x, h4[4 * jq + 0]);
      h4[4 * jq + 1] = fmaf(hv, w.y, h4[4 * jq + 1]);
      h4[4 * jq + 2] = fmaf(hv, w.z, h4[4 * jq + 2]);
      h4[4 * jq + 3] = fmaf(hv, w.w, h4[4 * jq + 3]);
    }
  }
  float p = cb4[0];
  #pragma unroll
  for (int k = 0; k < 8; k++) p = fmaf(leakyf(h4[k]), w4[k], p);
  out[i] = p;
}

extern "C" void kernel_launch(void* const* d_in, const int* in_sizes, int n_in,
                              void* d_out, int out_size, void* d_ws, size_t ws_size,
                              hipStream_t stream) {
  const float* disease_x   = (const float*)d_in[0];
  const float* drug_emb    = (const float*)d_in[1];
  const float* disease_emb = (const float*)d_in[2];
  const float* attr_emb    = (const float*)d_in[3];
  const float* dis_lin_w   = (const float*)d_in[4];
  const float* dis_lin_b   = (const float*)d_in[5];
  const float* mt_wl  = (const float*)d_in[6];
  const float* mt_bl  = (const float*)d_in[7];
  const float* mt_wr  = (const float*)d_in[8];
  const float* rmt_wl = (const float*)d_in[9];
  const float* rmt_bl = (const float*)d_in[10];
  const float* rmt_wr = (const float*)d_in[11];
  const float* ha_wl  = (const float*)d_in[12];
  const float* ha_bl  = (const float*)d_in[13];
  const float* ha_wr  = (const float*)d_in[14];
  const float* rha_wl = (const float*)d_in[15];
  const float* rha_bl = (const float*)d_in[16];
  const float* rha_wr = (const float*)d_in[17];
  const float* cw0 = (const float*)d_in[18];
  const float* cb0 = (const float*)d_in[19];
  const float* cw1 = (const float*)d_in[20];
  const float* cb1 = (const float*)d_in[21];
  const float* cw2 = (const float*)d_in[22];
  const float* cb2 = (const float*)d_in[23];
  const float* cw3 = (const float*)d_in[24];
  const float* cb3 = (const float*)d_in[25];
  const float* cw4 = (const float*)d_in[26];
  const float* cb4 = (const float*)d_in[27];
  const int* mt_src = (const int*)d_in[28];
  const int* mt_dst = (const int*)d_in[29];
  const int* ha_src = (const int*)d_in[30];
  const int* ha_dst = (const int*)d_in[31];
  const int* ell_src = (const int*)d_in[32];
  const int* ell_dst = (const int*)d_in[33];
  float* out = (float*)d_out;

  const long long ATTR_S = (long long)N_ATTR * HC;
  const long long W_S = HC * HC;

  // ---------- workspace carve ----------
  float* fws = (float*)d_ws;
  size_t o = 0;
  float* x_drug = fws + o; o += (size_t)N_DRUG * HC;
  float* x_dis  = fws + o; o += (size_t)N_DIS * HC;
  float* x_attr = fws + o; o += (size_t)T_ATTR * N_ATTR * HC;
  float* Ydis   = fws + o; o += (size_t)N_DIS * HC;          // | contiguous region
  float* Yattr  = fws + o; o += (size_t)T_ATTR * N_ATTR * HC;// | overlaid by hist
  float* m2dis  = fws + o; o += (size_t)N_DIS * HC;          // | (4.864M ints needed,
  float* m2a    = fws + o; o += (size_t)T_ATTR * N_ATTR * HC;// |  6.656M floats avail)
  float* accd   = fws + o; o += (size_t)N_DRUG * HC;
  float* Wc     = fws + o; o += HC * HC;
  float* biasc  = fws + o; o += HC;
  float* Ucls   = fws + o; o += (size_t)N_DRUG * 64;
  float* Vcls   = fws + o; o += (size_t)N_DIS * 64;
  int* iws = (int*)(fws + o);
  int* off = iws;                               // OFF_TOT = 304018
  int* val_mt_dst = off + OFF_TOT;              // 500000
  int* val_mt_src = val_mt_dst + E_MT;          // 500000
  int* val_ha_dst = val_mt_src + E_MT;          // 8*100000
  int* val_ha_src = val_ha_dst + (size_t)T_ATTR * E_HA; // 8*100000
  int* hist = (int*)Ydis;   // 4.864M ints, dead outside CSR build

  dim3 b256(256);
  // ---------- CSR build (LDS histograms, source-blocked sub-segments) ----------
  k_hist<<<dim3(NB, 1, 46), b256, 0, stream>>>(mt_src, mt_dst, ha_src, ha_dst, hist,
                                               val_mt_dst, val_mt_src, val_ha_dst, val_ha_src);
  k_blkpfx<<<dim3((N_DRUG + 255) / 256, 1, 46), b256, 0, stream>>>(mt_src, mt_dst, ha_src, ha_dst, hist, off,
                                                                   val_mt_dst, val_mt_src, val_ha_dst, val_ha_src);
  k_scan_bins<<<18, 1024, 0, stream>>>(off);
  k_fill2<<<dim3(NB, 1, 46), b256, 0, stream>>>(mt_src, mt_dst, ha_src, ha_dst, hist, off,
                                                val_mt_dst, val_mt_src, val_ha_dst, val_ha_src);

  // ---------- node init ----------
  k_dis0<<<N_DIS, 128, 0, stream>>>(disease_x, dis_lin_w, dis_lin_b, disease_emb, x_dis);

  for (int l = 0; l < 2; l++) {
    const float* xd = l ? (const float*)x_drug : drug_emb;
    const float* xa = l ? (const float*)x_attr : attr_emb;
    const float* mt_wl_l  = mt_wl  + (size_t)l * W_S;
    const float* mt_bl_l  = mt_bl  + (size_t)l * HC;
    const float* mt_wr_l  = mt_wr  + (size_t)l * W_S;
    const float* rmt_wl_l = rmt_wl + (size_t)l * W_S;
    const float* ha_wl_l  = ha_wl  + (size_t)l * T_ATTR * W_S;
    const float* ha_bl_l  = ha_bl  + (size_t)l * T_ATTR * HC;
    const float* ha_wr_l  = ha_wr  + (size_t)l * T_ATTR * W_S;
    const float* rha_wl_l = rha_wl + (size_t)l * T_ATTR * W_S;

    k_wc<<<64, 256, 0, stream>>>(rmt_wr + (size_t)l * W_S, rha_wr + (size_t)l * T_ATTR * W_S,
                                 rmt_bl + (size_t)l * HC, rha_bl + (size_t)l * T_ATTR * HC, Wc, biasc);

    // pre-transform GEMMs on the small side
    {
      GemmJobs J{};
      J.j[0] = {x_dis, rmt_wl_l, nullptr, nullptr, nullptr, nullptr, Ydis, N_DIS, 0};
      for (int t = 0; t < T_ATTR; t++)
        J.j[1 + t] = {xa + (size_t)t * ATTR_S, rha_wl_l + (size_t)t * W_S,
                      nullptr, nullptr, nullptr, nullptr, Yattr + (size_t)t * ATTR_S, N_ATTR, 0};
      k_gemm_multi<<<dim3((N_DIS + 63) / 64, 1, 9), b256, 0, stream>>>(J);
    }

    // all gathers of this layer (source-block phased)
    k_seg_mega<<<dim3((46000 + 3) / 4, 1, 1), b256, 0, stream>>>(
        off, val_mt_dst, val_mt_src, val_ha_dst, val_ha_src,
        xd, Ydis, Yattr, m2dis, accd, m2a);

    // combine GEMMs
    {
      GemmJobs J{};
      J.j[0] = {xd, Wc, nullptr, nullptr, biasc, accd, x_drug, N_DRUG, 1};
      J.j[1] = {m2dis, mt_wl_l, x_dis, mt_wr_l, mt_bl_l, nullptr, x_dis, N_DIS, 1};
      for (int t = 0; t < T_ATTR; t++)
        J.j[2 + t] = {m2a + (size_t)t * ATTR_S, ha_wl_l + (size_t)t * W_S,
                      xa + (size_t)t * ATTR_S, ha_wr_l + (size_t)t * W_S,
                      ha_bl_l + (size_t)t * HC, nullptr, x_attr + (size_t)t * ATTR_S, N_ATTR, 1};
      k_gemm_multi<<<dim3((N_DRUG + 63) / 64, 1, 10), b256, 0, stream>>>(J);
    }
  }

  // ---------- classifier: U/V precompute then per-edge tail ----------
  {
    G64Job ju = {x_drug, cw0, cb0, Ucls, N_DRUG};
    G64Job jv = {x_dis, cw0 + 128 * 64, nullptr, Vcls, N_DIS};
    k_gemm64<<<dim3((N_DRUG + 63) / 64, 1, 2), b256, 0, stream>>>(ju, jv);
    k_tail<<<dim3((E_LBL + 255) / 256, 1, 1), b256, 0, stream>>>(
        Ucls, Vcls, ell_src, ell_dst,
        cw1, cb1, cw2, cb2, cw3, cb3, cw4, cb4, out, E_LBL);
  }
}

// Round 8
// 571.402 us; speedup vs baseline: 1.2940x; 1.2940x over previous
//
#include <hip/hip_runtime.h>

#define N_DRUG 20000
#define N_DIS  10000
#define N_ATTR 2000
#define T_ATTR 8
#define E_MT   500000
#define E_HA   100000
#define E_LBL  200000
#define HC     128
#define NB     16   // blocks per edge segment in CSR build

__device__ __forceinline__ float leakyf(float x) { return x >= 0.f ? x : 0.01f * x; }

// bf16 helpers: RNE encode, exact decode
__device__ __forceinline__ unsigned short f2bf(float f) {
  unsigned int u = __float_as_uint(f);
  return (unsigned short)((u + 0x7fffu + ((u >> 16) & 1u)) >> 16);
}
__device__ __forceinline__ float bflo(unsigned int u) { return __uint_as_float(u << 16); }
__device__ __forceinline__ float bfhi(unsigned int u) { return __uint_as_float(u & 0xffff0000u); }

// ---------------- CSR build (R6 structure: 18 segments, LDS histograms) ----------------
// cnt/off layout: 0: mt_dst(10000) | 1: mt_src(20000) | 2-9: ha_dst[t](2000) | 10-17: ha_src[t](20000)
// off: 0 (10001) | 10001 (20001) | 30002 + t*2001 | 46010 + t*20001  (total 206018)
#define HB0 0
#define HB1 160000
#define HB2(t) (480000 + (t) * 32000)
#define HB10(t) (736000 + (t) * 320000)

struct Seg { const int* key; const int* oth; int n; int bins; int obase; int hbase; int* val; };

__device__ __forceinline__ Seg seg_resolve(int z,
    const int* mt_src, const int* mt_dst, const int* ha_src, const int* ha_dst,
    int* vmd, int* vms, int* vhd, int* vhs) {
  Seg s;
  if (z == 0)      { s.key = mt_dst; s.oth = mt_src; s.n = E_MT; s.bins = N_DIS;  s.obase = 0;     s.hbase = HB0;        s.val = vmd; }
  else if (z == 1) { s.key = mt_src; s.oth = mt_dst; s.n = E_MT; s.bins = N_DRUG; s.obase = 10001; s.hbase = HB1;        s.val = vms; }
  else if (z < 10) { int t = z - 2;
    s.key = ha_dst + (size_t)t * E_HA; s.oth = ha_src + (size_t)t * E_HA; s.n = E_HA;
    s.bins = N_ATTR; s.obase = 30002 + t * 2001; s.hbase = HB2(t); s.val = vhd + (size_t)t * E_HA; }
  else { int t = z - 10;
    s.key = ha_src + (size_t)t * E_HA; s.oth = ha_dst + (size_t)t * E_HA; s.n = E_HA;
    s.bins = N_DRUG; s.obase = 46010 + t * 20001; s.hbase = HB10(t); s.val = vhs + (size_t)t * E_HA; }
  return s;
}

__device__ __forceinline__ void seg_geom(int z, int& bins, int& obase, int& hbase) {
  if (z == 0)      { bins = N_DIS;  obase = 0;     hbase = HB0; }
  else if (z == 1) { bins = N_DRUG; obase = 10001; hbase = HB1; }
  else if (z < 10) { int t = z - 2;  bins = N_ATTR; obase = 30002 + t * 2001;  hbase = HB2(t); }
  else             { int t = z - 10; bins = N_DRUG; obase = 46010 + t * 20001; hbase = HB10(t); }
}

__global__ __launch_bounds__(256) void k_hist(
    const int* __restrict__ mt_src, const int* __restrict__ mt_dst,
    const int* __restrict__ ha_src, const int* __restrict__ ha_dst,
    int* __restrict__ hist,
    int* vmd, int* vms, int* vhd, int* vhs) {
  Seg s = seg_resolve(blockIdx.z, mt_src, mt_dst, ha_src, ha_dst, vmd, vms, vhd, vhs);
  __shared__ int h[N_DRUG];
  int tid = threadIdx.x, b = blockIdx.x;
  for (int i = tid; i < s.bins; i += 256) h[i] = 0;
  __syncthreads();
  int ch = (s.n + NB - 1) / NB;
  int lo = b * ch, hi = min(s.n, lo + ch);
  for (int i = lo + tid; i < hi; i += 256) atomicAdd(&h[s.key[i]], 1);
  __syncthreads();
  int* hz = hist + s.hbase + (size_t)b * s.bins;
  for (int i = tid; i < s.bins; i += 256) hz[i] = h[i];
}

__global__ __launch_bounds__(256) void k_blkpfx(int* __restrict__ hist, int* __restrict__ off) {
  int bins, obase, hbase;
  seg_geom(blockIdx.z, bins, obase, hbase);
  int i = blockIdx.x * 256 + threadIdx.x;
  if (i >= bins) return;
  int run = 0;
  #pragma unroll
  for (int b = 0; b < NB; b++) {
    int idx = hbase + b * bins + i;
    int v = hist[idx];
    hist[idx] = run;
    run += v;
  }
  off[obase + i] = run;
}

__global__ __launch_bounds__(1024) void k_scan_bins(int* __restrict__ off) {
  int bins, obase, hbase;
  seg_geom(blockIdx.x, bins, obase, hbase);
  __shared__ int ssum[1024];
  int tid = threadIdx.x;
  int per = (bins + 1023) >> 10;
  int lo = min(bins, tid * per), hi = min(bins, lo + per);
  int s = 0;
  for (int i = lo; i < hi; i++) s += off[obase + i];
  ssum[tid] = s;
  __syncthreads();
  if (tid == 0) {
    int run = 0;
    for (int i = 0; i < 1024; i++) { int v = ssum[i]; ssum[i] = run; run += v; }
    off[obase + bins] = run;
  }
  __syncthreads();
  int run = ssum[tid];
  for (int i = lo; i < hi; i++) {
    int v = off[obase + i];
    off[obase + i] = run;
    run += v;
  }
}

__global__ __launch_bounds__(256) void k_fill2(
    const int* __restrict__ mt_src, const int* __restrict__ mt_dst,
    const int* __restrict__ ha_src, const int* __restrict__ ha_dst,
    const int* __restrict__ hist, const int* __restrict__ off,
    int* vmd, int* vms, int* vhd, int* vhs) {
  Seg s = seg_resolve(blockIdx.z, mt_src, mt_dst, ha_src, ha_dst, vmd, vms, vhd, vhs);
  __shared__ int h[N_DRUG];
  int tid = threadIdx.x, b = blockIdx.x;
  const int* hz = hist + s.hbase + (size_t)b * s.bins;
  const int* oz = off + s.obase;
  for (int i = tid; i < s.bins; i += 256) h[i] = hz[i] + oz[i];
  __syncthreads();
  int ch = (s.n + NB - 1) / NB;
  int lo = b * ch, hi = min(s.n, lo + ch);
  for (int i = lo + tid; i < hi; i += 256) {
    int pos = atomicAdd(&h[s.key[i]], 1);
    s.val[pos] = s.oth[i];
  }
}

// ---------------- x_dis init ----------------
__global__ void k_dis0(const float* __restrict__ dx, const float* __restrict__ w,
                       const float* __restrict__ b, const float* __restrict__ emb,
                       float* __restrict__ out) {
  int i = blockIdx.x;
  int j = threadIdx.x;
  float s = b[j] + emb[(size_t)i * HC + j];
  #pragma unroll
  for (int k = 0; k < 10; k++) s += dx[i * 10 + k] * w[k * HC + j];
  out[(size_t)i * HC + j] = s;
}

// ---------------- Wc = rmt_wr + sum_t rha_wr ; biasc = rmt_bl + sum_t rha_bl ----------------
__global__ void k_wc(const float* __restrict__ wr_main, const float* __restrict__ wr_t,
                     const float* __restrict__ bl_main, const float* __restrict__ bl_t,
                     float* __restrict__ Wc, float* __restrict__ biasc) {
  int i = blockIdx.x * blockDim.x + threadIdx.x;
  if (i < HC * HC) {
    float s = wr_main[i];
    #pragma unroll
    for (int t = 0; t < T_ATTR; t++) s += wr_t[(size_t)t * HC * HC + i];
    Wc[i] = s;
  }
  if (i < HC) {
    float s = bl_main[i];
    #pragma unroll
    for (int t = 0; t < T_ATTR; t++) s += bl_t[t * HC + i];
    biasc[i] = s;
  }
}

// ---------------- f32 -> bf16 convert (4 elems/thread) ----------------
__global__ __launch_bounds__(256) void k_cvt(const float* __restrict__ src,
                                             unsigned short* __restrict__ dst, int n4) {
  int i = blockIdx.x * 256 + threadIdx.x;
  if (i >= n4) return;
  float4 v = ((const float4*)src)[i];
  uint2 w;
  w.x = (unsigned int)f2bf(v.x) | ((unsigned int)f2bf(v.y) << 16);
  w.y = (unsigned int)f2bf(v.z) | ((unsigned int)f2bf(v.w) << 16);
  ((uint2*)dst)[i] = w;
}

// ---------------- unroll-8 gather accumulate from bf16 table ----------------
// lane reads one uint = elements {2*lane, 2*lane+1} of the 128-elem row (256B/row)
__device__ __forceinline__ void gacc_b(const unsigned short* __restrict__ X, const int* __restrict__ val,
                                       int b, int e, int lane, float& ax, float& ay) {
  int i = b;
  for (; i + 8 <= e; i += 8) {
    unsigned int v[8];
    #pragma unroll
    for (int q = 0; q < 8; q++) {
      int n = val[i + q];
      v[q] = ((const unsigned int*)(X + (size_t)n * HC))[lane];
    }
    #pragma unroll
    for (int q = 0; q < 8; q++) { ax += bflo(v[q]); ay += bfhi(v[q]); }
  }
  for (; i < e; i++) {
    unsigned int v = ((const unsigned int*)(X + (size_t)val[i] * HC))[lane];
    ax += bflo(v); ay += bfhi(v);
  }
}

// ---------------- mega segment-mean: all gathers of one layer (bf16 tables, f32 out) ----------------
// wave w: [0,10000) m2dis | [10000,30000) drug merged (mt + 8*ha) | [30000,46000) m2a
__global__ __launch_bounds__(256) void k_seg_mega(
    const int* __restrict__ off,
    const int* __restrict__ vmt_dst, const int* __restrict__ vmt_src,
    const int* __restrict__ vha_dst, const int* __restrict__ vha_src,
    const unsigned short* __restrict__ xdb, const unsigned short* __restrict__ Ydisb,
    const unsigned short* __restrict__ Yattrb,
    float* __restrict__ m2dis, float* __restrict__ accd, float* __restrict__ m2a) {
  int lane = threadIdx.x & 63;
  int lane2 = lane * 2;
  int w = blockIdx.x * 4 + (threadIdx.x >> 6);
  if (w < N_DIS) {
    int d = w;
    int b = off[d], e = off[d + 1];
    float ax = 0.f, ay = 0.f;
    gacc_b(xdb, vmt_dst, b, e, lane, ax, ay);
    int c = e - b;
    float inv = 1.f / (float)(c > 0 ? c : 1);
    *(float2*)(m2dis + (size_t)d * HC + lane2) = make_float2(ax * inv, ay * inv);
  } else if (w < N_DIS + N_DRUG) {
    int d = w - N_DIS;
    float sx = 0.f, sy = 0.f;
    {
      int b = off[10001 + d], e = off[10001 + d + 1];
      float ax = 0.f, ay = 0.f;
      gacc_b(Ydisb, vmt_src, b, e, lane, ax, ay);
      int c = e - b;
      float inv = 1.f / (float)(c > 0 ? c : 1);
      sx += ax * inv; sy += ay * inv;
    }
    for (int t = 0; t < T_ATTR; t++) {
      int ob = 46010 + t * 20001;
      int b = off[ob + d], e = off[ob + d + 1];
      float ax = 0.f, ay = 0.f;
      gacc_b(Yattrb + (size_t)t * N_ATTR * HC, vha_src + (size_t)t * E_HA, b, e, lane, ax, ay);
      int c = e - b;
      float inv = 1.f / (float)(c > 0 ? c : 1);
      sx += ax * inv; sy += ay * inv;
    }
    *(float2*)(accd + (size_t)d * HC + lane2) = make_float2(sx, sy);
  } else {
    int idx = w - (N_DIS + N_DRUG);
    int t = idx / N_ATTR, r = idx - t * N_ATTR;
    int ob = 30002 + t * 2001;
    int b = off[ob + r], e = off[ob + r + 1];
    float ax = 0.f, ay = 0.f;
    gacc_b(xdb, vha_dst + (size_t)t * E_HA, b, e, lane, ax, ay);
    int c = e - b;
    float inv = 1.f / (float)(c > 0 ? c : 1);
    *(float2*)(m2a + ((size_t)t * N_ATTR + r) * HC + lane2) = make_float2(ax * inv, ay * inv);
  }
}

// ---------------- generalized batched GEMM ----------------
// D = [leaky]( A1@B1 [+ A2@B2] [+ ACC] [+ bias] ); bf16out: D is ushort* (RNE)
struct GemmJob {
  const float* A1; const float* B1;
  const float* A2; const float* B2;
  const float* bias; const float* ACC;
  float* D;
  int M; int leaky; int bf16out;
};
struct GemmJobs { GemmJob j[10]; };

__global__ __launch_bounds__(256) void k_gemm_multi(GemmJobs jobs) {
  GemmJob jb = jobs.j[blockIdx.z];
  int m0 = blockIdx.x * 64;
  if (m0 >= jb.M) return;
  __shared__ float As[16][68];
  __shared__ float Bs[16][132];
  int tid = threadIdx.x;
  int tx = tid & 31, ty = tid >> 5;
  float acc[8][4];
  #pragma unroll
  for (int i = 0; i < 8; i++)
    #pragma unroll
    for (int j = 0; j < 4; j++) acc[i][j] = 0.f;

  int K = jb.A2 ? 256 : 128;
  for (int kk = 0; kk < K; kk += 16) {
    const float* A = (kk < 128) ? jb.A1 : jb.A2;
    const float* B = (kk < 128) ? jb.B1 : jb.B2;
    int kb = kk & 127;
    {
      int r = tid >> 2, kq = (tid & 3) * 4;
      int gr = m0 + r;
      float4 v = make_float4(0.f, 0.f, 0.f, 0.f);
      if (gr < jb.M) v = *(const float4*)(A + (size_t)gr * HC + kb + kq);
      As[kq + 0][r] = v.x; As[kq + 1][r] = v.y; As[kq + 2][r] = v.z; As[kq + 3][r] = v.w;
    }
    #pragma unroll
    for (int i = 0; i < 2; i++) {
      int idx = i * 256 + tid;
      int k = idx >> 5, c = (idx & 31) * 4;
      *(float4*)&Bs[k][c] = *(const float4*)(B + (size_t)(kb + k) * HC + c);
    }
    __syncthreads();
    #pragma unroll
    for (int k = 0; k < 16; k++) {
      float4 a0 = *(const float4*)&As[k][ty * 8];
      float4 a1 = *(const float4*)&As[k][ty * 8 + 4];
      float4 bv = *(const float4*)&Bs[k][tx * 4];
      float av[8] = {a0.x, a0.y, a0.z, a0.w, a1.x, a1.y, a1.z, a1.w};
      float bb[4] = {bv.x, bv.y, bv.z, bv.w};
      #pragma unroll
      for (int i = 0; i < 8; i++)
        #pragma unroll
        for (int j = 0; j < 4; j++) acc[i][j] += av[i] * bb[j];
    }
    __syncthreads();
  }

  int c0 = tx * 4;
  float4 bs = make_float4(0.f, 0.f, 0.f, 0.f);
  if (jb.bias) bs = *(const float4*)(jb.bias + c0);
  #pragma unroll
  for (int i = 0; i < 8; i++) {
    int gr = m0 + ty * 8 + i;
    if (gr >= jb.M) break;
    float r0 = acc[i][0] + bs.x, r1 = acc[i][1] + bs.y, r2 = acc[i][2] + bs.z, r3 = acc[i][3] + bs.w;
    if (jb.ACC) {
      float4 ac = *(const float4*)(jb.ACC + (size_t)gr * HC + c0);
      r0 += ac.x; r1 += ac.y; r2 += ac.z; r3 += ac.w;
    }
    if (jb.leaky) { r0 = leakyf(r0); r1 = leakyf(r1); r2 = leakyf(r2); r3 = leakyf(r3); }
    if (jb.bf16out) {
      unsigned short* Db = (unsigned short*)jb.D;
      uint2 w;
      w.x = (unsigned int)f2bf(r0) | ((unsigned int)f2bf(r1) << 16);
      w.y = (unsigned int)f2bf(r2) | ((unsigned int)f2bf(r3) << 16);
      *(uint2*)(Db + (size_t)gr * 128 + c0) = w;
    } else {
      float4 rv = make_float4(r0, r1, r2, r3);
      *(float4*)(jb.D + (size_t)gr * 128 + c0) = rv;
    }
  }
}

// ---------------- classifier head GEMMs ----------------
struct G64Job { const float* X; const float* W; const float* bias; float* D; int M; };

__global__ __launch_bounds__(256) void k_gemm64(G64Job j0, G64Job j1) {
  G64Job jb = blockIdx.z ? j1 : j0;
  int m0 = blockIdx.x * 64;
  if (m0 >= jb.M) return;
  __shared__ float As[16][68];
  __shared__ float Bs[16][68];
  int tid = threadIdx.x;
  int tx = tid & 15, ty = tid >> 4;
  float acc[4][4];
  #pragma unroll
  for (int i = 0; i < 4; i++)
    #pragma unroll
    for (int j = 0; j < 4; j++) acc[i][j] = 0.f;

  for (int kk = 0; kk < 128; kk += 16) {
    {
      int r = tid >> 2, kq = (tid & 3) * 4;
      int gr = m0 + r;
      float4 v = make_float4(0.f, 0.f, 0.f, 0.f);
      if (gr < jb.M) v = *(const float4*)(jb.X + (size_t)gr * HC + kk + kq);
      As[kq + 0][r] = v.x; As[kq + 1][r] = v.y; As[kq + 2][r] = v.z; As[kq + 3][r] = v.w;
    }
    {
      int k = tid >> 4, c = (tid & 15) * 4;
      *(float4*)&Bs[k][c] = *(const float4*)(jb.W + (size_t)(kk + k) * 64 + c);
    }
    __syncthreads();
    #pragma unroll
    for (int k = 0; k < 16; k++) {
      float4 a = *(const float4*)&As[k][ty * 4];
      float4 b = *(const float4*)&Bs[k][tx * 4];
      float av[4] = {a.x, a.y, a.z, a.w};
      float bb[4] = {b.x, b.y, b.z, b.w};
      #pragma unroll
      for (int i = 0; i < 4; i++)
        #pragma unroll
        for (int j = 0; j < 4; j++) acc[i][j] += av[i] * bb[j];
    }
    __syncthreads();
  }
  float4 bs = make_float4(0.f, 0.f, 0.f, 0.f);
  if (jb.bias) bs = *(const float4*)(jb.bias + tx * 4);
  #pragma unroll
  for (int i = 0; i < 4; i++) {
    int gr = m0 + ty * 4 + i;
    if (gr < jb.M) {
      float4 r = make_float4(acc[i][0] + bs.x, acc[i][1] + bs.y, acc[i][2] + bs.z, acc[i][3] + bs.w);
      *(float4*)(jb.D + (size_t)gr * 64 + tx * 4) = r;
    }
  }
}

// ---------------- per-edge tail MLP (LDS weights, fully unrolled, registers only) ----------------
__global__ __launch_bounds__(256) void k_tail(
    const float* __restrict__ U, const float* __restrict__ V,
    const int* __restrict__ es, const int* __restrict__ ed,
    const float* __restrict__ cw1, const float* __restrict__ cb1,
    const float* __restrict__ cw2, const float* __restrict__ cb2,
    const float* __restrict__ cw3, const float* __restrict__ cb3,
    const float* __restrict__ cw4, const float* __restrict__ cb4,
    float* __restrict__ out, int n) {
  __shared__ float w1[64 * 32];
  __shared__ float w2[32 * 16];
  __shared__ float w3[16 * 8];
  __shared__ float w4[8];
  __shared__ float b1[32], b2[16], b3[8];
  int tid = threadIdx.x;
  #pragma unroll
  for (int q = 0; q < 8; q++) w1[tid + q * 256] = cw1[tid + q * 256];
  #pragma unroll
  for (int q = 0; q < 2; q++) w2[tid + q * 256] = cw2[tid + q * 256];
  if (tid < 128) w3[tid] = cw3[tid];
  if (tid < 8)  w4[tid] = cw4[tid];
  if (tid < 32) b1[tid] = cb1[tid];
  if (tid < 16) b2[tid] = cb2[tid];
  if (tid < 8)  b3[tid] = cb3[tid];
  __syncthreads();
  int i = blockIdx.x * 256 + tid;
  if (i >= n) return;
  int s = es[i], d = ed[i];
  const float4* up = (const float4*)(U + (size_t)s * 64);
  const float4* vp = (const float4*)(V + (size_t)d * 64);
  float h1[64];
  #pragma unroll
  for (int q = 0; q < 16; q++) {
    float4 a = up[q], b = vp[q];
    h1[4 * q + 0] = leakyf(a.x + b.x);
    h1[4 * q + 1] = leakyf(a.y + b.y);
    h1[4 * q + 2] = leakyf(a.z + b.z);
    h1[4 * q + 3] = leakyf(a.w + b.w);
  }
  float h2[32];
  #pragma unroll
  for (int j = 0; j < 32; j++) h2[j] = b1[j];
  #pragma unroll
  for (int k = 0; k < 64; k++) {
    float hv = h1[k];
    #pragma unroll
    for (int jq = 0; jq < 8; jq++) {
      float4 w = *(const float4*)&w1[k * 32 + jq * 4];
      h2[4 * jq + 0] = fmaf(hv, w.x, h2[4 * jq + 0]);
      h2[4 * jq + 1] = fmaf(hv, w.y, h2[4 * jq + 1]);
      h2[4 * jq + 2] = fmaf(hv, w.z, h2[4 * jq + 2]);
      h2[4 * jq + 3] = fmaf(hv, w.w, h2[4 * jq + 3]);
    }
  }
  float h3[16];
  #pragma unroll
  for (int j = 0; j < 16; j++) h3[j] = b2[j];
  #pragma unroll
  for (int k = 0; k < 32; k++) {
    float hv = leakyf(h2[k]);
    #pragma unroll
    for (int jq = 0; jq < 4; jq++) {
      float4 w = *(const float4*)&w2[k * 16 + jq * 4];
      h3[4 * jq + 0] = fmaf(hv, w.x, h3[4 * jq + 0]);
      h3[4 * jq + 1] = fmaf(hv, w.y, h3[4 * jq + 1]);
      h3[4 * jq + 2] = fmaf(hv, w.z, h3[4 * jq + 2]);
      h3[4 * jq + 3] = fmaf(hv, w.w, h3[4 * jq + 3]);
    }
  }
  float h4[8];
  #pragma unroll
  for (int j = 0; j < 8; j++) h4[j] = b3[j];
  #pragma unroll
  for (int k = 0; k < 16; k++) {
    float hv = leakyf(h3[k]);
    #pragma unroll
    for (int jq = 0; jq < 2; jq++) {
      float4 w = *(const float4*)&w3[k * 8 + jq * 4];
      h4[4 * jq + 0] = fmaf(hv, w.x, h4[4 * jq + 0]);
      h4[4 * jq + 1] = fmaf(hv, w.y, h4[4 * jq + 1]);
      h4[4 * jq + 2] = fmaf(hv, w.z, h4[4 * jq + 2]);
      h4[4 * jq + 3] = fmaf(hv, w.w, h4[4 * jq + 3]);
    }
  }
  float p = cb4[0];
  #pragma unroll
  for (int k = 0; k < 8; k++) p = fmaf(leakyf(h4[k]), w4[k], p);
  out[i] = p;
}

extern "C" void kernel_launch(void* const* d_in, const int* in_sizes, int n_in,
                              void* d_out, int out_size, void* d_ws, size_t ws_size,
                              hipStream_t stream) {
  const float* disease_x   = (const float*)d_in[0];
  const float* drug_emb    = (const float*)d_in[1];
  const float* disease_emb = (const float*)d_in[2];
  const float* attr_emb    = (const float*)d_in[3];
  const float* dis_lin_w   = (const float*)d_in[4];
  const float* dis_lin_b   = (const float*)d_in[5];
  const float* mt_wl  = (const float*)d_in[6];
  const float* mt_bl  = (const float*)d_in[7];
  const float* mt_wr  = (const float*)d_in[8];
  const float* rmt_wl = (const float*)d_in[9];
  const float* rmt_bl = (const float*)d_in[10];
  const float* rmt_wr = (const float*)d_in[11];
  const float* ha_wl  = (const float*)d_in[12];
  const float* ha_bl  = (const float*)d_in[13];
  const float* ha_wr  = (const float*)d_in[14];
  const float* rha_wl = (const float*)d_in[15];
  const float* rha_bl = (const float*)d_in[16];
  const float* rha_wr = (const float*)d_in[17];
  const float* cw0 = (const float*)d_in[18];
  const float* cb0 = (const float*)d_in[19];
  const float* cw1 = (const float*)d_in[20];
  const float* cb1 = (const float*)d_in[21];
  const float* cw2 = (const float*)d_in[22];
  const float* cb2 = (const float*)d_in[23];
  const float* cw3 = (const float*)d_in[24];
  const float* cb3 = (const float*)d_in[25];
  const float* cw4 = (const float*)d_in[26];
  const float* cb4 = (const float*)d_in[27];
  const int* mt_src = (const int*)d_in[28];
  const int* mt_dst = (const int*)d_in[29];
  const int* ha_src = (const int*)d_in[30];
  const int* ha_dst = (const int*)d_in[31];
  const int* ell_src = (const int*)d_in[32];
  const int* ell_dst = (const int*)d_in[33];
  float* out = (float*)d_out;

  const long long ATTR_S = (long long)N_ATTR * HC;
  const long long W_S = HC * HC;

  // ---------- workspace carve ----------
  float* fws = (float*)d_ws;
  size_t o = 0;
  float* x_drug = fws + o; o += (size_t)N_DRUG * HC;
  float* x_dis  = fws + o; o += (size_t)N_DIS * HC;
  float* x_attr = fws + o; o += (size_t)T_ATTR * N_ATTR * HC;
  float* m2dis  = fws + o; o += (size_t)N_DIS * HC;          // | m2dis+m2a (3.328M floats)
  float* m2a    = fws + o; o += (size_t)T_ATTR * N_ATTR * HC;// | overlaid by hist (3.296M ints)
  float* accd   = fws + o; o += (size_t)N_DRUG * HC;
  float* Wc     = fws + o; o += HC * HC;
  float* biasc  = fws + o; o += HC;
  float* Ucls   = fws + o; o += (size_t)N_DRUG * 64;
  float* Vcls   = fws + o; o += (size_t)N_DIS * 64;
  unsigned short* xdb    = (unsigned short*)(fws + o);       // bf16 gather tables
  unsigned short* Ydisb  = xdb + (size_t)N_DRUG * HC;
  unsigned short* Yattrb = Ydisb + (size_t)N_DIS * HC;
  o += ((size_t)N_DRUG * HC + (size_t)N_DIS * HC + (size_t)T_ATTR * N_ATTR * HC) / 2;
  int* iws = (int*)(fws + o);
  int* off = iws;                               // 206018
  int* val_mt_dst = off + 206018;
  int* val_mt_src = val_mt_dst + E_MT;
  int* val_ha_dst = val_mt_src + E_MT;
  int* val_ha_src = val_ha_dst + (size_t)T_ATTR * E_HA;
  int* hist = (int*)m2dis;   // 3.296M ints over m2dis+m2a (dead during CSR build)

  dim3 b256(256);
  // ---------- CSR build ----------
  k_hist<<<dim3(NB, 1, 18), b256, 0, stream>>>(mt_src, mt_dst, ha_src, ha_dst, hist,
                                               val_mt_dst, val_mt_src, val_ha_dst, val_ha_src);
  k_blkpfx<<<dim3((N_DRUG + 255) / 256, 1, 18), b256, 0, stream>>>(hist, off);
  k_scan_bins<<<18, 1024, 0, stream>>>(off);
  k_fill2<<<dim3(NB, 1, 18), b256, 0, stream>>>(mt_src, mt_dst, ha_src, ha_dst, hist, off,
                                                val_mt_dst, val_mt_src, val_ha_dst, val_ha_src);

  // ---------- node init ----------
  k_dis0<<<N_DIS, 128, 0, stream>>>(disease_x, dis_lin_w, dis_lin_b, disease_emb, x_dis);

  for (int l = 0; l < 2; l++) {
    const float* xd = l ? (const float*)x_drug : drug_emb;
    const float* xa = l ? (const float*)x_attr : attr_emb;
    const float* mt_wl_l  = mt_wl  + (size_t)l * W_S;
    const float* mt_bl_l  = mt_bl  + (size_t)l * HC;
    const float* mt_wr_l  = mt_wr  + (size_t)l * W_S;
    const float* rmt_wl_l = rmt_wl + (size_t)l * W_S;
    const float* ha_wl_l  = ha_wl  + (size_t)l * T_ATTR * W_S;
    const float* ha_bl_l  = ha_bl  + (size_t)l * T_ATTR * HC;
    const float* ha_wr_l  = ha_wr  + (size_t)l * T_ATTR * W_S;
    const float* rha_wl_l = rha_wl + (size_t)l * T_ATTR * W_S;

    k_wc<<<64, 256, 0, stream>>>(rmt_wr + (size_t)l * W_S, rha_wr + (size_t)l * T_ATTR * W_S,
                                 rmt_bl + (size_t)l * HC, rha_bl + (size_t)l * T_ATTR * HC, Wc, biasc);

    // pre-transform GEMMs on the small side -> bf16 tables for the gather
    {
      GemmJobs J{};
      J.j[0] = {x_dis, rmt_wl_l, nullptr, nullptr, nullptr, nullptr, (float*)Ydisb, N_DIS, 0, 1};
      for (int t = 0; t < T_ATTR; t++)
        J.j[1 + t] = {xa + (size_t)t * ATTR_S, rha_wl_l + (size_t)t * W_S,
                      nullptr, nullptr, nullptr, nullptr,
                      (float*)(Yattrb + (size_t)t * ATTR_S), N_ATTR, 0, 1};
      k_gemm_multi<<<dim3((N_DIS + 63) / 64, 1, 9), b256, 0, stream>>>(J);
    }
    // xd -> bf16
    k_cvt<<<dim3((N_DRUG * HC / 4 + 255) / 256), b256, 0, stream>>>(xd, xdb, N_DRUG * HC / 4);

    // all gathers of this layer (bf16 tables, f32 accumulate)
    k_seg_mega<<<dim3((46000 + 3) / 4, 1, 1), b256, 0, stream>>>(
        off, val_mt_dst, val_mt_src, val_ha_dst, val_ha_src,
        xdb, Ydisb, Yattrb, m2dis, accd, m2a);

    // combine GEMMs (f32)
    {
      GemmJobs J{};
      J.j[0] = {xd, Wc, nullptr, nullptr, biasc, accd, x_drug, N_DRUG, 1, 0};
      J.j[1] = {m2dis, mt_wl_l, x_dis, mt_wr_l, mt_bl_l, nullptr, x_dis, N_DIS, 1, 0};
      for (int t = 0; t < T_ATTR; t++)
        J.j[2 + t] = {m2a + (size_t)t * ATTR_S, ha_wl_l + (size_t)t * W_S,
                      xa + (size_t)t * ATTR_S, ha_wr_l + (size_t)t * W_S,
                      ha_bl_l + (size_t)t * HC, nullptr, x_attr + (size_t)t * ATTR_S, N_ATTR, 1, 0};
      k_gemm_multi<<<dim3((N_DRUG + 63) / 64, 1, 10), b256, 0, stream>>>(J);
    }
  }

  // ---------- classifier: U/V precompute then per-edge tail ----------
  {
    G64Job ju = {x_drug, cw0, cb0, Ucls, N_DRUG};
    G64Job jv = {x_dis, cw0 + 128 * 64, nullptr, Vcls, N_DIS};
    k_gemm64<<<dim3((N_DRUG + 63) / 64, 1, 2), b256, 0, stream>>>(ju, jv);
    k_tail<<<dim3((E_LBL + 255) / 256, 1, 1), b256, 0, stream>>>(
        Ucls, Vcls, ell_src, ell_dst,
        cw1, cb1, cw2, cb2, cw3, cb3, cw4, cb4, out, E_LBL);
  }
}